// Round 2
// baseline (367.657 us; speedup 1.0000x reference)
//
#include <hip/hip_runtime.h>

// ---------- types ----------
typedef __attribute__((ext_vector_type(8))) short short8;     // 8 bf16 (4 VGPRs)
typedef __attribute__((ext_vector_type(4))) float floatx4;    // MFMA C/D
typedef __attribute__((ext_vector_type(4))) unsigned int uintx4;

// ---------- fp32 -> packed bf16x2 (RNE) ----------
#if __has_builtin(__builtin_amdgcn_cvt_pk_bf16_f32)
typedef __attribute__((ext_vector_type(2))) __bf16 bf16x2;
__device__ __forceinline__ unsigned int pk_bf16(float a, float b) {
  bf16x2 v = __builtin_amdgcn_cvt_pk_bf16_f32(a, b);
  return __builtin_bit_cast(unsigned int, v);
}
#else
__device__ __forceinline__ unsigned int bf16_1(float f) {
  unsigned int u = __builtin_bit_cast(unsigned int, f);
  return (u + 0x7fffu + ((u >> 16) & 1u)) >> 16;
}
__device__ __forceinline__ unsigned int pk_bf16(float a, float b) {
  return bf16_1(a) | (bf16_1(b) << 16);
}
#endif

// ============================================================
// Prepass: W [8][64][768] fp32  ->  bf16 B-fragments in MFMA lane order.
// Frag (mod, n16 in [0,32), ks in [0,24)): 64 lanes x 16B; lane l holds
// B[k = ks*32 + (l>>4)*8 + jj][n = n16*16 + (l&15)], jj=0..7, where
// B[k][n] = W[c][r][k], n = r*8 + c.
// Also biasPrep[mod*512 + n] = b[c*64 + r].
// ============================================================
__global__ __launch_bounds__(256) void prep_kernel(
    const float* __restrict__ Wi, const float* __restrict__ Wc, const float* __restrict__ Wd,
    const float* __restrict__ bi, const float* __restrict__ bc, const float* __restrict__ bd,
    unsigned int* __restrict__ Bprep, float* __restrict__ biasPrep) {
  const int t = blockIdx.x * 256 + threadIdx.x;  // 0 .. 147455
  const int l = t & 63;
  const int frag = t >> 6;              // 0 .. 2303
  const int mod = frag / 768;           // 32*24 frags per modality
  const int rem = frag - mod * 768;
  const int n16 = rem / 24;
  const int ks = rem - n16 * 24;
  const float* __restrict__ W = (mod == 0) ? Wi : ((mod == 1) ? Wc : Wd);

  const int n = n16 * 16 + (l & 15);
  const int r = n >> 3;
  const int c = n & 7;
  const int i0 = ks * 32 + (l >> 4) * 8;
  const float* src = W + (size_t)(c * 64 + r) * 768 + i0;
  float4 f0 = *(const float4*)(src);
  float4 f1 = *(const float4*)(src + 4);
  uintx4 p;
  p.x = pk_bf16(f0.x, f0.y);
  p.y = pk_bf16(f0.z, f0.w);
  p.z = pk_bf16(f1.x, f1.y);
  p.w = pk_bf16(f1.z, f1.w);
  ((uintx4*)Bprep)[frag * 64 + l] = p;

  if (t < 1536) {
    const int m2 = t >> 9;
    const int nn = t & 511;
    const float* bb = (m2 == 0) ? bi : ((m2 == 1) ? bc : bd);
    biasPrep[t] = bb[(nn & 7) * 64 + (nn >> 3)];
  }
}

// ============================================================
// Fused projection + squash — NO LDS, no barriers.
// Grid: 1536 blocks. XCD swizzle: the 4 bn-blocks of one (mod,bm) land on
// the same XCD (bx differing by 8/16/24) so L2 serves the A duplication.
// Block: 256 thr = 4 waves (2m x 2n); wave covers 64x64 = 4x4 frags of
// 16x16x32. A frags loaded per-lane straight from global (two dwordx4 of
// one x-row), cvt to bf16 in-reg. B frags from pre-swizzled Bprep (L2-hot).
// ============================================================
__global__ __launch_bounds__(256, 3) void caps_gemm(
    const float* __restrict__ x0, const float* __restrict__ x1, const float* __restrict__ x2,
    const uintx4* __restrict__ Bprep, const float* __restrict__ biasPrep,
    float* __restrict__ out) {
  const int tid = threadIdx.x;
  const int bx = blockIdx.x;
  // XCD-aware swizzle: xcd = bx&7; j = bx>>3; bn = j&3; tile = (j>>2)*8+xcd
  const int xcd = bx & 7;
  const int j = bx >> 3;
  const int bn = j & 3;
  const int tile = (j >> 2) * 8 + xcd;   // 0..383
  const int mod = tile >> 7;             // 0..2
  const int bm = tile & 127;             // 0..127
  const float* __restrict__ X = (mod == 0) ? x0 : ((mod == 1) ? x1 : x2);

  const int wid = tid >> 6;
  const int lane = tid & 63;
  const int ln = lane & 15;
  const int quad = lane >> 4;
  const int wm = wid & 1;
  const int wn = wid >> 1;

  // A: lane's fragment for m-tile mt, K-step ks lives at
  //    X[(bm*128 + wm*64 + mt*16 + ln)*768 + ks*32 + quad*8 .. +7]
  const float* aBase = X + (size_t)(bm * 128 + wm * 64 + ln) * 768 + quad * 8;

  // B fragment pointer (lane-indexed, pre-swizzled)
  const uintx4* bptr = Bprep + (size_t)((mod * 32 + bn * 8 + wn * 4) * 24) * 64 + lane;

  floatx4 acc[4][4] = {};

#pragma unroll 2
  for (int ks = 0; ks < 24; ++ks) {
    uintx4 bf[4];
#pragma unroll
    for (int nt = 0; nt < 4; ++nt) bf[nt] = bptr[(size_t)nt * (24 * 64) + ks * 64];

#pragma unroll
    for (int mt = 0; mt < 4; ++mt) {
      const float* ap = aBase + (size_t)mt * 16 * 768 + ks * 32;
      float4 f0 = *(const float4*)(ap);
      float4 f1 = *(const float4*)(ap + 4);
      uintx4 pa;
      pa.x = pk_bf16(f0.x, f0.y);
      pa.y = pk_bf16(f0.z, f0.w);
      pa.z = pk_bf16(f1.x, f1.y);
      pa.w = pk_bf16(f1.z, f1.w);
      short8 af = __builtin_bit_cast(short8, pa);
#pragma unroll
      for (int nt = 0; nt < 4; ++nt)
        acc[mt][nt] = __builtin_amdgcn_mfma_f32_16x16x32_bf16(
            af, __builtin_bit_cast(short8, bf[nt]), acc[mt][nt], 0, 0, 0);
    }
  }

  // --- epilogue: bias + squash (sum over 8 consecutive n = 8 lanes) + store
  const int nb = mod * 512 + bn * 128 + wn * 64 + ln;  // absolute out column
  float bias[4];
#pragma unroll
  for (int nt = 0; nt < 4; ++nt) bias[nt] = biasPrep[nb + nt * 16];

  const int mrow0 = bm * 128 + wm * 64 + quad * 4;
#pragma unroll
  for (int mt = 0; mt < 4; ++mt) {
    const size_t rbase = (size_t)(mrow0 + mt * 16) * 1536;
#pragma unroll
    for (int nt = 0; nt < 4; ++nt) {
      float* op = out + rbase + nb + nt * 16;
#pragma unroll
      for (int jj = 0; jj < 4; ++jj) {
        float u = acc[mt][nt][jj] + bias[nt];
        float s = u * u;
        s += __shfl_xor(s, 1);
        s += __shfl_xor(s, 2);
        s += __shfl_xor(s, 4);
        float sc = s / ((1.0f + s) * sqrtf(s + 1e-7f));
        op[(size_t)jj * 1536] = u * sc;
      }
    }
  }
}

// ============================================================
extern "C" void kernel_launch(void* const* d_in, const int* in_sizes, int n_in,
                              void* d_out, int out_size, void* d_ws, size_t ws_size,
                              hipStream_t stream) {
  const float* ximg = (const float*)d_in[0];
  const float* xcapt = (const float*)d_in[1];
  const float* xdct = (const float*)d_in[2];
  const float* Wi = (const float*)d_in[3];
  const float* bi = (const float*)d_in[4];
  const float* Wc = (const float*)d_in[5];
  const float* bc = (const float*)d_in[6];
  const float* Wd = (const float*)d_in[7];
  const float* bd = (const float*)d_in[8];

  unsigned int* Bprep = (unsigned int*)d_ws;                 // 2304 KiB
  float* biasPrep = (float*)((char*)d_ws + 2304 * 1024);     // 6 KiB

  hipLaunchKernelGGL(prep_kernel, dim3(576), dim3(256), 0, stream,
                     Wi, Wc, Wd, bi, bc, bd, Bprep, biasPrep);
  hipLaunchKernelGGL(caps_gemm, dim3(1536), dim3(256), 0, stream,
                     ximg, xcapt, xdct, (const uintx4*)Bprep, biasPrep, (float*)d_out);
}

// Round 3
// 299.327 us; speedup vs baseline: 1.2283x; 1.2283x over previous
//
#include <hip/hip_runtime.h>

// ---------- types ----------
typedef __attribute__((ext_vector_type(8))) short short8;     // 8 bf16 (4 VGPRs)
typedef __attribute__((ext_vector_type(4))) float floatx4;    // MFMA C/D
typedef __attribute__((ext_vector_type(4))) unsigned int uintx4;

// ---------- fp32 -> packed bf16x2 (RNE) ----------
#if __has_builtin(__builtin_amdgcn_cvt_pk_bf16_f32)
typedef __attribute__((ext_vector_type(2))) __bf16 bf16x2;
__device__ __forceinline__ unsigned int pk_bf16(float a, float b) {
  bf16x2 v = __builtin_amdgcn_cvt_pk_bf16_f32(a, b);
  return __builtin_bit_cast(unsigned int, v);
}
#else
__device__ __forceinline__ unsigned int bf16_1(float f) {
  unsigned int u = __builtin_bit_cast(unsigned int, f);
  return (u + 0x7fffu + ((u >> 16) & 1u)) >> 16;
}
__device__ __forceinline__ unsigned int pk_bf16(float a, float b) {
  return bf16_1(a) | (bf16_1(b) << 16);
}
#endif

// Fragment conventions (verified rounds 1-2, absmax 3.9e-3):
//   A-frag (16x16x32): lane(ln,quad) holds A[m=ln][k=quad*8+j], j=0..7
//   B-frag:            lane(ln,quad) holds B[n=ln][k=quad*8+j]  (B[k][n]=W[c][r][k], n=r*8+c)
//   C/D:               col=ln, row=quad*4+reg
//
// Aprep frag id: Fa = ((mod*256 + g)*24 + ks)*4 + mt   where m16 = g*4+mt
// Bprep frag id: Fb = ((mod*8  + h)*24 + ks)*4 + nt    where n16 = h*4+nt
// Each frag = 64 lanes x 16 B = 1 KB, stored at F*64+lane (uintx4 units).
// => the 4 mt (nt) frags of one (group, ks) are one contiguous 4 KB block.

// ============================================================
// Prepass W: [8][64][768] fp32 -> bf16 B-fragments; bias permuted to n-order.
// ============================================================
__global__ __launch_bounds__(256) void prep_w(
    const float* __restrict__ Wi, const float* __restrict__ Wc, const float* __restrict__ Wd,
    const float* __restrict__ bi, const float* __restrict__ bc, const float* __restrict__ bd,
    uintx4* __restrict__ Bprep, float* __restrict__ biasPrep) {
  const int t = blockIdx.x * 256 + threadIdx.x;  // 0 .. 147455
  const int l = t & 63;
  const int frag = t >> 6;             // 0 .. 2303
  const int nt = frag & 3;
  const int q = frag >> 2;
  const int ks = q % 24;
  const int q2 = q / 24;
  const int h = q2 & 7;
  const int mod = q2 >> 3;
  const int n16 = h * 4 + nt;
  const float* __restrict__ W = (mod == 0) ? Wi : ((mod == 1) ? Wc : Wd);

  const int n = n16 * 16 + (l & 15);
  const int r = n >> 3;
  const int c = n & 7;
  const int i0 = ks * 32 + (l >> 4) * 8;
  const float* src = W + (size_t)(c * 64 + r) * 768 + i0;
  float4 f0 = *(const float4*)(src);
  float4 f1 = *(const float4*)(src + 4);
  uintx4 p;
  p.x = pk_bf16(f0.x, f0.y);
  p.y = pk_bf16(f0.z, f0.w);
  p.z = pk_bf16(f1.x, f1.y);
  p.w = pk_bf16(f1.z, f1.w);
  Bprep[(size_t)frag * 64 + l] = p;

  if (t < 1536) {
    const int m2 = t >> 9;
    const int nn = t & 511;
    const float* bb = (m2 == 0) ? bi : ((m2 == 1) ? bc : bd);
    biasPrep[t] = bb[(nn & 7) * 64 + (nn >> 3)];
  }
}

// ============================================================
// Prepass X: [3][16384][768] fp32 -> bf16 A-fragments (streaming, mem-bound).
// Block = 4 waves = 4 consecutive frags (same group+ks, mt 0..3):
// reads 64 rows x 128 B window, writes 4 KB coalesced.
// ============================================================
__global__ __launch_bounds__(256) void prep_x(
    const float* __restrict__ x0, const float* __restrict__ x1, const float* __restrict__ x2,
    uintx4* __restrict__ Aprep) {
  const int f = blockIdx.x * 4 + (threadIdx.x >> 6);  // 0 .. 73727
  const int lane = threadIdx.x & 63;
  const int mt = f & 3;
  const int q = f >> 2;
  const int ks = q % 24;
  const int q2 = q / 24;       // mod*256 + g
  const int g = q2 & 255;
  const int mod = q2 >> 8;
  const int m16 = g * 4 + mt;
  const float* __restrict__ X = (mod == 0) ? x0 : ((mod == 1) ? x1 : x2);

  const float* src = X + (size_t)(m16 * 16 + (lane & 15)) * 768 + ks * 32 + (lane >> 4) * 8;
  float4 f0 = *(const float4*)(src);
  float4 f1 = *(const float4*)(src + 4);
  uintx4 p;
  p.x = pk_bf16(f0.x, f0.y);
  p.y = pk_bf16(f0.z, f0.w);
  p.z = pk_bf16(f1.x, f1.y);
  p.w = pk_bf16(f1.z, f1.w);
  Aprep[(size_t)f * 64 + lane] = p;
}

// ============================================================
// GEMM + squash. No LDS, no barriers, no in-loop cvt.
// Grid 1536: xcd=bx&7 ; j=bx>>3 ; bn=j&3 ; tile=(j>>2)*8+xcd (bn-blocks on
// same XCD for L2 reuse of A). Block = 4 waves (wm,wn), wave = 64x64 =
// 4x4 frags. Register double-buffered frag loads, prefetch distance 1.
// ============================================================
#define LOADK(ab, bb, ks)                         \
  {                                               \
    _Pragma("unroll") for (int t = 0; t < 4; ++t) \
    {                                             \
      ab[t] = ap0[(ks) * 256 + t * 64];           \
      bb[t] = bp0[(ks) * 256 + t * 64];           \
    }                                             \
  }

#define COMPK(ab, bb)                                                  \
  {                                                                    \
    _Pragma("unroll") for (int mt = 0; mt < 4; ++mt)                   \
    {                                                                  \
      short8 af = __builtin_bit_cast(short8, ab[mt]);                  \
      _Pragma("unroll") for (int nt = 0; nt < 4; ++nt)                 \
          acc[mt][nt] = __builtin_amdgcn_mfma_f32_16x16x32_bf16(       \
              af, __builtin_bit_cast(short8, bb[nt]), acc[mt][nt], 0,  \
              0, 0);                                                   \
    }                                                                  \
  }

__global__ __launch_bounds__(256, 3) void caps_gemm(
    const uintx4* __restrict__ Aprep, const uintx4* __restrict__ Bprep,
    const float* __restrict__ biasPrep, float* __restrict__ out) {
  const int tid = threadIdx.x;
  const int bx = blockIdx.x;
  const int xcd = bx & 7;
  const int j = bx >> 3;
  const int bn = j & 3;
  const int tile = (j >> 2) * 8 + xcd;  // 0..383
  const int mod = tile >> 7;
  const int bm = tile & 127;

  const int wid = tid >> 6;
  const int lane = tid & 63;
  const int ln = lane & 15;
  const int quad = lane >> 4;
  const int wm = wid & 1;
  const int wn = wid >> 1;

  const uintx4* ap0 = Aprep + (size_t)((mod * 256 + bm * 2 + wm) * 24) * 256 + lane;
  const uintx4* bp0 = Bprep + (size_t)((mod * 8 + bn * 2 + wn) * 24) * 256 + lane;

  floatx4 acc[4][4] = {};
  uintx4 a0[4], b0[4], a1[4], b1[4];

  LOADK(a0, b0, 0);
#pragma unroll 1
  for (int ks2 = 0; ks2 < 12; ++ks2) {
    const int ks = 2 * ks2;
    LOADK(a1, b1, ks + 1);
    COMPK(a0, b0);
    if (ks2 != 11) LOADK(a0, b0, ks + 2);
    COMPK(a1, b1);
  }

  // --- epilogue: bias + squash (8 consecutive n cols = 8 lanes) + store
  const int nb = mod * 512 + bn * 128 + wn * 64 + ln;
  float bias[4];
#pragma unroll
  for (int nt = 0; nt < 4; ++nt) bias[nt] = biasPrep[nb + nt * 16];

  const int mrow0 = bm * 128 + wm * 64 + quad * 4;
#pragma unroll
  for (int mt = 0; mt < 4; ++mt) {
    const size_t rbase = (size_t)(mrow0 + mt * 16) * 1536;
#pragma unroll
    for (int nt = 0; nt < 4; ++nt) {
      float* op = out + rbase + nb + nt * 16;
#pragma unroll
      for (int jj = 0; jj < 4; ++jj) {
        float u = acc[mt][nt][jj] + bias[nt];
        float s = u * u;
        s += __shfl_xor(s, 1);
        s += __shfl_xor(s, 2);
        s += __shfl_xor(s, 4);
        float sc = s / ((1.0f + s) * sqrtf(s + 1e-7f));
        op[(size_t)jj * 1536] = u * sc;
      }
    }
  }
}

// ============================================================
// Fallback GEMM (ws too small for Aprep): in-loop A cvt from X (round-2 path)
// ============================================================
__global__ __launch_bounds__(256, 3) void caps_gemm_fb(
    const float* __restrict__ x0, const float* __restrict__ x1, const float* __restrict__ x2,
    const uintx4* __restrict__ Bprep, const float* __restrict__ biasPrep,
    float* __restrict__ out) {
  const int tid = threadIdx.x;
  const int bx = blockIdx.x;
  const int xcd = bx & 7;
  const int j = bx >> 3;
  const int bn = j & 3;
  const int tile = (j >> 2) * 8 + xcd;
  const int mod = tile >> 7;
  const int bm = tile & 127;
  const float* __restrict__ X = (mod == 0) ? x0 : ((mod == 1) ? x1 : x2);

  const int wid = tid >> 6;
  const int lane = tid & 63;
  const int ln = lane & 15;
  const int quad = lane >> 4;
  const int wm = wid & 1;
  const int wn = wid >> 1;

  const float* aBase = X + (size_t)(bm * 128 + wm * 64 + ln) * 768 + quad * 8;
  const uintx4* bp0 = Bprep + (size_t)((mod * 8 + bn * 2 + wn) * 24) * 256 + lane;

  floatx4 acc[4][4] = {};
#pragma unroll 2
  for (int ks = 0; ks < 24; ++ks) {
    uintx4 bf[4];
#pragma unroll
    for (int nt = 0; nt < 4; ++nt) bf[nt] = bp0[ks * 256 + nt * 64];
#pragma unroll
    for (int mt = 0; mt < 4; ++mt) {
      const float* ap = aBase + (size_t)mt * 16 * 768 + ks * 32;
      float4 f0 = *(const float4*)(ap);
      float4 f1 = *(const float4*)(ap + 4);
      uintx4 pa;
      pa.x = pk_bf16(f0.x, f0.y);
      pa.y = pk_bf16(f0.z, f0.w);
      pa.z = pk_bf16(f1.x, f1.y);
      pa.w = pk_bf16(f1.z, f1.w);
      short8 af = __builtin_bit_cast(short8, pa);
#pragma unroll
      for (int nt = 0; nt < 4; ++nt)
        acc[mt][nt] = __builtin_amdgcn_mfma_f32_16x16x32_bf16(
            af, __builtin_bit_cast(short8, bf[nt]), acc[mt][nt], 0, 0, 0);
    }
  }

  const int nb = mod * 512 + bn * 128 + wn * 64 + ln;
  float bias[4];
#pragma unroll
  for (int nt = 0; nt < 4; ++nt) bias[nt] = biasPrep[nb + nt * 16];

  const int mrow0 = bm * 128 + wm * 64 + quad * 4;
#pragma unroll
  for (int mt = 0; mt < 4; ++mt) {
    const size_t rbase = (size_t)(mrow0 + mt * 16) * 1536;
#pragma unroll
    for (int nt = 0; nt < 4; ++nt) {
      float* op = out + rbase + nb + nt * 16;
#pragma unroll
      for (int jj = 0; jj < 4; ++jj) {
        float u = acc[mt][nt][jj] + bias[nt];
        float s = u * u;
        s += __shfl_xor(s, 1);
        s += __shfl_xor(s, 2);
        s += __shfl_xor(s, 4);
        float sc = s / ((1.0f + s) * sqrtf(s + 1e-7f));
        op[(size_t)jj * 1536] = u * sc;
      }
    }
  }
}

// ============================================================
extern "C" void kernel_launch(void* const* d_in, const int* in_sizes, int n_in,
                              void* d_out, int out_size, void* d_ws, size_t ws_size,
                              hipStream_t stream) {
  const float* ximg = (const float*)d_in[0];
  const float* xcapt = (const float*)d_in[1];
  const float* xdct = (const float*)d_in[2];
  const float* Wi = (const float*)d_in[3];
  const float* bi = (const float*)d_in[4];
  const float* Wc = (const float*)d_in[5];
  const float* bc = (const float*)d_in[6];
  const float* Wd = (const float*)d_in[7];
  const float* bd = (const float*)d_in[8];

  const size_t szA = 73728ull * 1024;      // 72 MiB of A-fragments
  const size_t szB = 2304ull * 1024;       // 2.25 MiB of B-fragments
  const size_t need = szA + szB + 6144;

  if (ws_size >= need) {
    uintx4* Aprep = (uintx4*)d_ws;
    uintx4* Bprep = (uintx4*)((char*)d_ws + szA);
    float* biasPrep = (float*)((char*)d_ws + szA + szB);
    hipLaunchKernelGGL(prep_x, dim3(18432), dim3(256), 0, stream,
                       ximg, xcapt, xdct, Aprep);
    hipLaunchKernelGGL(prep_w, dim3(576), dim3(256), 0, stream,
                       Wi, Wc, Wd, bi, bc, bd, Bprep, biasPrep);
    hipLaunchKernelGGL(caps_gemm, dim3(1536), dim3(256), 0, stream,
                       Aprep, Bprep, biasPrep, (float*)d_out);
  } else {
    uintx4* Bprep = (uintx4*)d_ws;
    float* biasPrep = (float*)((char*)d_ws + szB);
    hipLaunchKernelGGL(prep_w, dim3(576), dim3(256), 0, stream,
                       Wi, Wc, Wd, bi, bc, bd, Bprep, biasPrep);
    hipLaunchKernelGGL(caps_gemm_fb, dim3(1536), dim3(256), 0, stream,
                       ximg, xcapt, xdct, Bprep, biasPrep, (float*)d_out);
  }
}

// Round 4
// 281.768 us; speedup vs baseline: 1.3048x; 1.0623x over previous
//
#include <hip/hip_runtime.h>

// ---------- types ----------
typedef __attribute__((ext_vector_type(8))) short short8;     // 8 bf16 (4 VGPRs)
typedef __attribute__((ext_vector_type(4))) float floatx4;    // MFMA C/D
typedef __attribute__((ext_vector_type(4))) unsigned int uintx4;

// ---------- fp32 -> packed bf16x2 (RNE) ----------
#if __has_builtin(__builtin_amdgcn_cvt_pk_bf16_f32)
typedef __attribute__((ext_vector_type(2))) __bf16 bf16x2;
__device__ __forceinline__ unsigned int pk_bf16(float a, float b) {
  bf16x2 v = __builtin_amdgcn_cvt_pk_bf16_f32(a, b);
  return __builtin_bit_cast(unsigned int, v);
}
#else
__device__ __forceinline__ unsigned int bf16_1(float f) {
  unsigned int u = __builtin_bit_cast(unsigned int, f);
  return (u + 0x7fffu + ((u >> 16) & 1u)) >> 16;
}
__device__ __forceinline__ unsigned int pk_bf16(float a, float b) {
  return bf16_1(a) | (bf16_1(b) << 16);
}
#endif

// Fragment conventions (verified rounds 1-3, absmax 3.9e-3):
//   A-frag (16x16x32): lane(ln,quad) holds A[m=ln][k=quad*8+j], j=0..7
//   B-frag:            lane(ln,quad) holds B[n=ln][k=quad*8+j]  (B[k][n]=W[c][r][k], n=r*8+c)
//   C/D:               col=ln, row=quad*4+reg
// Bprep frag id: Fb = ((mod*8 + h)*24 + ks)*4 + nt, n16 = h*4+nt; frag = 64 lanes x 16B.

// ============================================================
// Prepass W: [8][64][768] fp32 -> bf16 B-fragments; bias permuted to n-order.
// ============================================================
__global__ __launch_bounds__(256) void prep_w(
    const float* __restrict__ Wi, const float* __restrict__ Wc, const float* __restrict__ Wd,
    const float* __restrict__ bi, const float* __restrict__ bc, const float* __restrict__ bd,
    uintx4* __restrict__ Bprep, float* __restrict__ biasPrep) {
  const int t = blockIdx.x * 256 + threadIdx.x;  // 0 .. 147455
  const int l = t & 63;
  const int frag = t >> 6;             // 0 .. 2303
  const int nt = frag & 3;
  const int q = frag >> 2;
  const int ks = q % 24;
  const int q2 = q / 24;
  const int h = q2 & 7;
  const int mod = q2 >> 3;
  const int n16 = h * 4 + nt;
  const float* __restrict__ W = (mod == 0) ? Wi : ((mod == 1) ? Wc : Wd);

  const int n = n16 * 16 + (l & 15);
  const int r = n >> 3;
  const int c = n & 7;
  const int i0 = ks * 32 + (l >> 4) * 8;
  const float* src = W + (size_t)(c * 64 + r) * 768 + i0;
  float4 f0 = *(const float4*)(src);
  float4 f1 = *(const float4*)(src + 4);
  uintx4 p;
  p.x = pk_bf16(f0.x, f0.y);
  p.y = pk_bf16(f0.z, f0.w);
  p.z = pk_bf16(f1.x, f1.y);
  p.w = pk_bf16(f1.z, f1.w);
  Bprep[(size_t)frag * 64 + l] = p;

  if (t < 1536) {
    const int m2 = t >> 9;
    const int nn = t & 511;
    const float* bb = (m2 == 0) ? bi : ((m2 == 1) ? bc : bd);
    biasPrep[t] = bb[(nn & 7) * 64 + (nn >> 3)];
  }
}

// ============================================================
// Fused: stage A (m=32 x K=768) ONCE as bf16 frags in LDS (48 KB, slot-XOR
// swizzled), one barrier, then a barrier-free 24-step K-loop:
// per wave-step 2 ds_read_b128 (A) + 8 L2-hot B-frag loads + 16 MFMA,
// register double-buffered. Epilogue fuses bias + squash.
// Grid 1536 = 3 mods x 512 m-tiles; block = 4 waves, wave = 32 x 128.
// ============================================================
#define LOADA(aa, kk)                                                        \
  {                                                                          \
    _Pragma("unroll") for (int mt = 0; mt < 2; ++mt)                         \
        aa[mt] = Afr[((kk) * 2 + mt) * 64 +                                  \
                     ((ln ^ (((kk) * 4 + quad) & 15)) + (quad << 4))];       \
  }

#define LOADB(bb, kk)                                                        \
  {                                                                          \
    _Pragma("unroll") for (int n2 = 0; n2 < 8; ++n2)                         \
        bb[n2] = bbase[(size_t)((n2 >> 2) * 96 + (kk) * 4 + (n2 & 3)) * 64]; \
  }

#define COMP(aa, bb)                                                     \
  {                                                                      \
    _Pragma("unroll") for (int mt = 0; mt < 2; ++mt)                     \
    {                                                                    \
      short8 af = __builtin_bit_cast(short8, aa[mt]);                    \
      _Pragma("unroll") for (int n2 = 0; n2 < 8; ++n2)                   \
          acc[mt][n2] = __builtin_amdgcn_mfma_f32_16x16x32_bf16(         \
              af, __builtin_bit_cast(short8, bb[n2]), acc[mt][n2], 0, 0, \
              0);                                                        \
    }                                                                    \
  }

__global__ __launch_bounds__(256, 3) void caps_fused(
    const float* __restrict__ x0, const float* __restrict__ x1, const float* __restrict__ x2,
    const uintx4* __restrict__ Bprep, const float* __restrict__ biasPrep,
    float* __restrict__ out) {
  __shared__ unsigned long long As64[48 * 128];  // 48 frags x 64 slots x 16 B

  const int tid = threadIdx.x;
  const int bx = blockIdx.x;
  const int mod = bx >> 9;           // 1536 = 3 x 512
  const int bm = bx & 511;           // m-tile (32 rows)
  const float* __restrict__ X = (mod == 0) ? x0 : ((mod == 1) ? x1 : x2);

  // ---- one-shot staging: 32 rows x 768 cols fp32, coalesced ----
  const float* src = X + (size_t)bm * 32 * 768;
#pragma unroll
  for (int i = 0; i < 24; ++i) {
    const int idx = i * 1024 + tid * 4;          // flat float index in tile
    float4 f = *(const float4*)(src + idx);
    const int m = (unsigned)idx / 768u;
    const int k = idx - m * 768;
    const int ks = k >> 5;
    const int kk = k & 31;
    const int qk = kk >> 3;                      // quad of k
    const int jh = (kk >> 2) & 1;                // which 8-byte half
    const int mt = m >> 4;
    const int lnn = m & 15;
    const int p = (ks * 4 + qk) & 15;            // slot-XOR spread
    const int slot = (lnn ^ p) + (qk << 4);
    unsigned long long w =
        ((unsigned long long)pk_bf16(f.z, f.w) << 32) | pk_bf16(f.x, f.y);
    As64[(((ks * 2 + mt) * 64 + slot) << 1) + jh] = w;
  }
  __syncthreads();  // the ONLY barrier

  const int lane = tid & 63;
  const int ln = lane & 15;
  const int quad = lane >> 4;
  const int wv = tid >> 6;  // wave id: n16-range wv*8 .. wv*8+7

  const uintx4* Afr = (const uintx4*)As64;
  const uintx4* bbase = Bprep + (size_t)((mod * 8 + wv * 2) * 24) * 4 * 64 + lane;

  floatx4 acc[2][8] = {};
  uintx4 a0[2], a1[2], b0[8], b1[8];

  LOADA(a0, 0);
  LOADB(b0, 0);
#pragma unroll 1
  for (int ks2 = 0; ks2 < 12; ++ks2) {
    const int ks = 2 * ks2;
    LOADA(a1, ks + 1);
    LOADB(b1, ks + 1);
    COMP(a0, b0);
    if (ks2 != 11) {
      LOADA(a0, ks + 2);
      LOADB(b0, ks + 2);
    }
    COMP(a1, b1);
  }

  // ---- epilogue: bias + squash (8 consecutive n cols = 8 lanes) + store ----
  const int col0 = mod * 512 + wv * 128 + ln;
  float bias[8];
#pragma unroll
  for (int n2 = 0; n2 < 8; ++n2) bias[n2] = biasPrep[col0 + n2 * 16];

#pragma unroll
  for (int mt = 0; mt < 2; ++mt) {
    const size_t rbase = (size_t)(bm * 32 + mt * 16 + quad * 4) * 1536;
#pragma unroll
    for (int n2 = 0; n2 < 8; ++n2) {
      float* op = out + rbase + col0 + n2 * 16;
#pragma unroll
      for (int jj = 0; jj < 4; ++jj) {
        float u = acc[mt][n2][jj] + bias[n2];
        float s = u * u;
        s += __shfl_xor(s, 1);
        s += __shfl_xor(s, 2);
        s += __shfl_xor(s, 4);
        float sc = s / ((1.0f + s) * sqrtf(s + 1e-7f));
        op[(size_t)jj * 1536] = u * sc;
      }
    }
  }
}

// ============================================================
extern "C" void kernel_launch(void* const* d_in, const int* in_sizes, int n_in,
                              void* d_out, int out_size, void* d_ws, size_t ws_size,
                              hipStream_t stream) {
  const float* ximg = (const float*)d_in[0];
  const float* xcapt = (const float*)d_in[1];
  const float* xdct = (const float*)d_in[2];
  const float* Wi = (const float*)d_in[3];
  const float* bi = (const float*)d_in[4];
  const float* Wc = (const float*)d_in[5];
  const float* bc = (const float*)d_in[6];
  const float* Wd = (const float*)d_in[7];
  const float* bd = (const float*)d_in[8];

  uintx4* Bprep = (uintx4*)d_ws;                           // 2.25 MiB
  float* biasPrep = (float*)((char*)d_ws + 2304 * 1024);   // 6 KiB

  hipLaunchKernelGGL(prep_w, dim3(576), dim3(256), 0, stream,
                     Wi, Wc, Wd, bi, bc, bd, Bprep, biasPrep);
  hipLaunchKernelGGL(caps_fused, dim3(1536), dim3(256), 0, stream,
                     ximg, xcapt, xdct, (const uintx4*)Bprep, biasPrep,
                     (float*)d_out);
}